// Round 1
// baseline (1297.960 us; speedup 1.0000x reference)
//
#include <hip/hip_runtime.h>
#include <cstdint>
#include <cstddef>

typedef unsigned short u16;
typedef unsigned int u32;

typedef short bf16x8_t __attribute__((ext_vector_type(8)));
typedef float f32x4_t __attribute__((ext_vector_type(4)));

__device__ __forceinline__ u16 f2bf(float f) {
  u32 u = __float_as_uint(f);
  u += 0x7fffu + ((u >> 16) & 1u);   // round-to-nearest-even
  return (u16)(u >> 16);
}
__device__ __forceinline__ float bf_lo(u32 w) { return __uint_as_float(w << 16); }
__device__ __forceinline__ float bf_hi(u32 w) { return __uint_as_float(w & 0xffff0000u); }
__device__ __forceinline__ u32 pack2(float lo, float hi) {
  return (u32)f2bf(lo) | ((u32)f2bf(hi) << 16);
}

// ---------------- casts ----------------
__global__ __launch_bounds__(256) void cast_f32_to_bf16(
    const float* __restrict__ in, u16* __restrict__ out, int n4) {
  int i = blockIdx.x * 256 + threadIdx.x;
  if (i >= n4) return;
  float4 f = ((const float4*)in)[i];
  uint2 o;
  o.x = pack2(f.x, f.y);
  o.y = pack2(f.z, f.w);
  ((uint2*)out)[i] = o;
}

// Wt[n*K + k] = bf16(W[k*N + n])   (transpose + cast; small matrices)
__global__ __launch_bounds__(256) void wt_cast(
    const float* __restrict__ W, u16* __restrict__ Wt, int K, int N) {
  int id = blockIdx.x * 256 + threadIdx.x;
  if (id >= K * N) return;
  int n_ = id / K;
  int k = id - n_ * K;
  Wt[id] = f2bf(W[(size_t)k * N + n_]);
}

// ---------------- CSR build ----------------
__global__ __launch_bounds__(256) void zero_i32(int* __restrict__ p, int n) {
  int i = blockIdx.x * 256 + threadIdx.x;
  if (i < n) p[i] = 0;
}

__global__ __launch_bounds__(256) void count_kernel(
    const int* __restrict__ src, const int* __restrict__ dst,
    int* __restrict__ cb, int* __restrict__ cu, int E) {
  int e = blockIdx.x * 256 + threadIdx.x;
  if (e >= E) return;
  atomicAdd(&cb[dst[e]], 1);
  atomicAdd(&cu[src[e]], 1);
}

// single-block exclusive scan: cnt_cur holds counts on input, offsets on output;
// rp gets offsets plus rp[n] = total.
__global__ __launch_bounds__(1024) void exscan_kernel(
    int* __restrict__ cnt_cur, int* __restrict__ rp, int n) {
  __shared__ int buf[1024];
  __shared__ int carry_s;
  const int tid = threadIdx.x;
  if (tid == 0) carry_s = 0;
  __syncthreads();
  for (int base = 0; base < n; base += 8192) {
    int idx = base + tid * 8;
    int v[8];
    int vs = 0;
#pragma unroll
    for (int q = 0; q < 8; ++q) {
      v[q] = (idx + q < n) ? cnt_cur[idx + q] : 0;
      vs += v[q];
    }
    buf[tid] = vs;
    __syncthreads();
    for (int off = 1; off < 1024; off <<= 1) {
      int t = (tid >= off) ? buf[tid - off] : 0;
      __syncthreads();
      buf[tid] += t;
      __syncthreads();
    }
    int cold = carry_s;
    int total = buf[1023];
    int run = cold + buf[tid] - vs;
#pragma unroll
    for (int q = 0; q < 8; ++q) {
      if (idx + q < n) { rp[idx + q] = run; cnt_cur[idx + q] = run; }
      run += v[q];
    }
    __syncthreads();
    if (tid == 0) carry_s = cold + total;
    __syncthreads();
  }
  if (tid == 0) rp[n] = carry_s;
}

__global__ __launch_bounds__(256) void fill_kernel(
    const int* __restrict__ src, const int* __restrict__ dst,
    int* __restrict__ cb, int* __restrict__ cu,
    int* __restrict__ colb, int* __restrict__ colu, int E) {
  int e = blockIdx.x * 256 + threadIdx.x;
  if (e >= E) return;
  int s = src[e], d = dst[e];
  colb[atomicAdd(&cb[d], 1)] = s;
  colu[atomicAdd(&cu[s], 1)] = d;
}

// ---------------- segment mean (wave per dst row) ----------------
__device__ __forceinline__ void acc4(float* a, uint2 p) {
  a[0] += bf_lo(p.x); a[1] += bf_hi(p.x);
  a[2] += bf_lo(p.y); a[3] += bf_hi(p.y);
}
__device__ __forceinline__ void acc8(float* a, uint4 p) {
  a[0] += bf_lo(p.x); a[1] += bf_hi(p.x);
  a[2] += bf_lo(p.y); a[3] += bf_hi(p.y);
  a[4] += bf_lo(p.z); a[5] += bf_hi(p.z);
  a[6] += bf_lo(p.w); a[7] += bf_hi(p.w);
}

template <int D>
__global__ __launch_bounds__(256) void agg_mean_kernel(
    const u16* __restrict__ x, const int* __restrict__ rp,
    const int* __restrict__ col, u16* __restrict__ out, int M) {
  constexpr int V = D / 64;  // bf16 elems per lane (4 or 8)
  int wid = blockIdx.x * 4 + (threadIdx.x >> 6);
  if (wid >= M) return;
  int lane = threadIdx.x & 63;
  int s = rp[wid];
  int e = rp[wid + 1];
  float a[V];
#pragma unroll
  for (int q = 0; q < V; ++q) a[q] = 0.0f;
  const u16* xo = x + (size_t)lane * V;
  int t = s;
  if constexpr (V == 4) {
    for (; t + 2 <= e; t += 2) {
      int j0 = col[t], j1 = col[t + 1];
      uint2 p0 = *(const uint2*)(xo + (size_t)j0 * D);
      uint2 p1 = *(const uint2*)(xo + (size_t)j1 * D);
      acc4(a, p0);
      acc4(a, p1);
    }
    if (t < e) {
      uint2 p = *(const uint2*)(xo + (size_t)col[t] * D);
      acc4(a, p);
    }
  } else {
    for (; t + 2 <= e; t += 2) {
      int j0 = col[t], j1 = col[t + 1];
      uint4 p0 = *(const uint4*)(xo + (size_t)j0 * D);
      uint4 p1 = *(const uint4*)(xo + (size_t)j1 * D);
      acc8(a, p0);
      acc8(a, p1);
    }
    if (t < e) {
      uint4 p = *(const uint4*)(xo + (size_t)col[t] * D);
      acc8(a, p);
    }
  }
  int deg = e - s;
  float sc = 1.0f / (float)(deg > 0 ? deg : 1);
  u16* op = out + (size_t)wid * D + (size_t)lane * V;
  if constexpr (V == 4) {
    uint2 o;
    o.x = pack2(a[0] * sc, a[1] * sc);
    o.y = pack2(a[2] * sc, a[3] * sc);
    *(uint2*)op = o;
  } else {
    uint4 o;
    o.x = pack2(a[0] * sc, a[1] * sc);
    o.y = pack2(a[2] * sc, a[3] * sc);
    o.z = pack2(a[4] * sc, a[5] * sc);
    o.w = pack2(a[6] * sc, a[7] * sc);
    *(uint4*)op = o;
  }
}

// ---------------- fused dual-A GEMM: C = relu(A1@B1 + A2@B2 + bias) ----------------
// A1,A2: [M][K] bf16 row-major. B1t,B2t: [N][K] bf16 (pre-transposed weights).
// 128x128 tile, 4 waves in 2x2, each wave 64x64 via 4x4 mfma_f32_16x16x32_bf16.
template <int OUT_BF16>
__global__ __launch_bounds__(256) void gemm2_kernel(
    const u16* __restrict__ A1, const u16* __restrict__ A2,
    const u16* __restrict__ B1t, const u16* __restrict__ B2t,
    const float* __restrict__ bias, void* __restrict__ Cout,
    int M, int N, int K) {
  __shared__ u16 As[128][40];  // stride 40 breaks LDS bank aliasing
  __shared__ u16 Bs[128][40];
  const int m0 = blockIdx.x * 128;
  const int n0 = blockIdx.y * 128;
  const int tid = threadIdx.x;
  const int w = tid >> 6;
  const int lane = tid & 63;
  const int wm = (w & 1) << 6;
  const int wn = (w >> 1) << 6;
  const int quad = lane >> 4;
  const int l16 = lane & 15;
  const int srow = tid >> 2;         // 0..63
  const int scol = (tid & 3) << 3;   // 0,8,16,24

  f32x4_t acc[4][4];
#pragma unroll
  for (int i = 0; i < 4; ++i)
#pragma unroll
    for (int j = 0; j < 4; ++j)
#pragma unroll
      for (int r = 0; r < 4; ++r) acc[i][j][r] = 0.0f;

#pragma unroll 1
  for (int pass = 0; pass < 2; ++pass) {
    const u16* A = pass ? A2 : A1;
    const u16* Bt = pass ? B2t : B1t;
#pragma unroll 1
    for (int k0 = 0; k0 < K; k0 += 32) {
      __syncthreads();
#pragma unroll
      for (int rr = 0; rr < 2; ++rr) {
        int row = srow + (rr << 6);
        int gm = m0 + row;
        uint4 va = {0u, 0u, 0u, 0u};
        if (gm < M) va = *(const uint4*)(A + (size_t)gm * K + k0 + scol);
        *(uint4*)(&As[row][scol]) = va;
        uint4 vb = *(const uint4*)(Bt + (size_t)(n0 + row) * K + k0 + scol);
        *(uint4*)(&Bs[row][scol]) = vb;
      }
      __syncthreads();
      bf16x8_t af[4], bfv[4];
#pragma unroll
      for (int i = 0; i < 4; ++i)
        af[i] = *(const bf16x8_t*)(&As[wm + i * 16 + l16][quad << 3]);
#pragma unroll
      for (int j = 0; j < 4; ++j)
        bfv[j] = *(const bf16x8_t*)(&Bs[wn + j * 16 + l16][quad << 3]);
#pragma unroll
      for (int i = 0; i < 4; ++i)
#pragma unroll
        for (int j = 0; j < 4; ++j)
          acc[i][j] = __builtin_amdgcn_mfma_f32_16x16x32_bf16(af[i], bfv[j], acc[i][j], 0, 0, 0);
    }
  }

  // epilogue: C[row=(lane>>4)*4+r][col=lane&15] per 16x16 tile
#pragma unroll
  for (int i = 0; i < 4; ++i) {
    int row = m0 + wm + i * 16 + (quad << 2);
#pragma unroll
    for (int j = 0; j < 4; ++j) {
      int colg = n0 + wn + j * 16 + l16;
      float b = bias[colg];
#pragma unroll
      for (int r = 0; r < 4; ++r) {
        if (row + r < M) {
          float v = fmaxf(acc[i][j][r] + b, 0.0f);
          if (OUT_BF16)
            ((u16*)Cout)[(size_t)(row + r) * N + colg] = f2bf(v);
          else
            ((float*)Cout)[(size_t)(row + r) * N + colg] = v;
        }
      }
    }
  }
}

// ---------------- launch ----------------
extern "C" void kernel_launch(void* const* d_in, const int* in_sizes, int n_in,
                              void* d_out, int out_size, void* d_ws, size_t ws_size,
                              hipStream_t stream) {
  const int DIN = 256, DH = 512, DOUT = 256;
  const int NU = in_sizes[0] / DIN;
  const int NB = in_sizes[1] / DIN;
  const int E = in_sizes[2];

  const float* x_user = (const float*)d_in[0];
  const float* x_biz = (const float*)d_in[1];
  const int* e_src = (const int*)d_in[2];
  const int* e_dst = (const int*)d_in[3];
  const float* W1l_ub = (const float*)d_in[4];
  const float* W1r_ub = (const float*)d_in[5];
  const float* b1_ub = (const float*)d_in[6];
  const float* W1l_bu = (const float*)d_in[7];
  const float* W1r_bu = (const float*)d_in[8];
  const float* b1_bu = (const float*)d_in[9];
  const float* W2l_ub = (const float*)d_in[10];
  const float* W2r_ub = (const float*)d_in[11];
  const float* b2_ub = (const float*)d_in[12];
  const float* W2l_bu = (const float*)d_in[13];
  const float* W2r_bu = (const float*)d_in[14];
  const float* b2_bu = (const float*)d_in[15];

  char* base = (char*)d_ws;
  size_t off = 0;
  auto alloc = [&](size_t bytes) -> char* {
    char* r = base + off;
    off += (bytes + 255) & ~(size_t)255;
    return r;
  };

  int* rp_b = (int*)alloc((size_t)(NB + 1) * 4);
  int* rp_u = (int*)alloc((size_t)(NU + 1) * 4);
  int* cur_b = (int*)alloc((size_t)NB * 4);
  int* cur_u = (int*)alloc((size_t)NU * 4);
  int* col_b = (int*)alloc((size_t)E * 4);
  int* col_u = (int*)alloc((size_t)E * 4);
  u16* w1l_ub_t = (u16*)alloc((size_t)DIN * DH * 2);
  u16* w1r_ub_t = (u16*)alloc((size_t)DIN * DH * 2);
  u16* w1l_bu_t = (u16*)alloc((size_t)DIN * DH * 2);
  u16* w1r_bu_t = (u16*)alloc((size_t)DIN * DH * 2);
  u16* w2l_ub_t = (u16*)alloc((size_t)DH * DOUT * 2);
  u16* w2r_ub_t = (u16*)alloc((size_t)DH * DOUT * 2);
  u16* w2l_bu_t = (u16*)alloc((size_t)DH * DOUT * 2);
  u16* w2r_bu_t = (u16*)alloc((size_t)DH * DOUT * 2);
  // region P: phase 1 = x_bf + mean1; phase 2 = mean2 (aliased)
  u16* x_user_bf = (u16*)alloc((size_t)NU * DIN * 2);  // 51.2 MB
  u16* x_biz_bf = (u16*)alloc((size_t)NB * DIN * 2);   // 25.6 MB
  u16* m1_biz = (u16*)alloc((size_t)NB * DIN * 2);     // 25.6 MB
  u16* m1_user = (u16*)alloc((size_t)NU * DIN * 2);    // 51.2 MB
  u16* h_biz = (u16*)alloc((size_t)NB * DH * 2);       // 51.2 MB
  u16* h_user = (u16*)alloc((size_t)NU * DH * 2);      // 102.4 MB
  // aliases (all sub-buffers are 256B-aligned multiples, so contiguous):
  u16* m2_biz = x_user_bf;  // needs NB*DH*2 = 51.2 MB  == NU*DIN*2
  u16* m2_user = x_biz_bf;  // needs NU*DH*2 = 102.4 MB == x_biz+m1_biz+m1_user
  if (off > ws_size) return;  // workspace too small; nothing safe to do

  // 1. cast node features to bf16
  {
    int n4u = NU * DIN / 4, n4b = NB * DIN / 4;
    cast_f32_to_bf16<<<(n4u + 255) / 256, 256, 0, stream>>>(x_user, x_user_bf, n4u);
    cast_f32_to_bf16<<<(n4b + 255) / 256, 256, 0, stream>>>(x_biz, x_biz_bf, n4b);
  }
  // 2. transpose+cast weights
  {
    int kn1 = DIN * DH, kn2 = DH * DOUT;
    wt_cast<<<(kn1 + 255) / 256, 256, 0, stream>>>(W1l_ub, w1l_ub_t, DIN, DH);
    wt_cast<<<(kn1 + 255) / 256, 256, 0, stream>>>(W1r_ub, w1r_ub_t, DIN, DH);
    wt_cast<<<(kn1 + 255) / 256, 256, 0, stream>>>(W1l_bu, w1l_bu_t, DIN, DH);
    wt_cast<<<(kn1 + 255) / 256, 256, 0, stream>>>(W1r_bu, w1r_bu_t, DIN, DH);
    wt_cast<<<(kn2 + 255) / 256, 256, 0, stream>>>(W2l_ub, w2l_ub_t, DH, DOUT);
    wt_cast<<<(kn2 + 255) / 256, 256, 0, stream>>>(W2r_ub, w2r_ub_t, DH, DOUT);
    wt_cast<<<(kn2 + 255) / 256, 256, 0, stream>>>(W2l_bu, w2l_bu_t, DH, DOUT);
    wt_cast<<<(kn2 + 255) / 256, 256, 0, stream>>>(W2r_bu, w2r_bu_t, DH, DOUT);
  }
  // 3. CSR build (both directions share edge list)
  zero_i32<<<(NB + 255) / 256, 256, 0, stream>>>(cur_b, NB);
  zero_i32<<<(NU + 255) / 256, 256, 0, stream>>>(cur_u, NU);
  count_kernel<<<(E + 255) / 256, 256, 0, stream>>>(e_src, e_dst, cur_b, cur_u, E);
  exscan_kernel<<<1, 1024, 0, stream>>>(cur_b, rp_b, NB);
  exscan_kernel<<<1, 1024, 0, stream>>>(cur_u, rp_u, NU);
  fill_kernel<<<(E + 255) / 256, 256, 0, stream>>>(e_src, e_dst, cur_b, cur_u, col_b, col_u, E);
  // 4. layer-1 aggregation (mean)
  agg_mean_kernel<256><<<(NB + 3) / 4, 256, 0, stream>>>(x_user_bf, rp_b, col_b, m1_biz, NB);
  agg_mean_kernel<256><<<(NU + 3) / 4, 256, 0, stream>>>(x_biz_bf, rp_u, col_u, m1_user, NU);
  // 5. layer-1 GEMMs: h = relu(mean@W_l + b + x@W_r), bf16 out
  {
    dim3 gb((NB + 127) / 128, DH / 128);
    gemm2_kernel<1><<<gb, 256, 0, stream>>>(m1_biz, x_biz_bf, w1l_ub_t, w1r_ub_t, b1_ub,
                                            h_biz, NB, DH, DIN);
    dim3 gu((NU + 127) / 128, DH / 128);
    gemm2_kernel<1><<<gu, 256, 0, stream>>>(m1_user, x_user_bf, w1l_bu_t, w1r_bu_t, b1_bu,
                                            h_user, NU, DH, DIN);
  }
  // 6. layer-2 aggregation (mean) — writes alias dead layer-1 buffers
  agg_mean_kernel<512><<<(NB + 3) / 4, 256, 0, stream>>>(h_user, rp_b, col_b, m2_biz, NB);
  agg_mean_kernel<512><<<(NU + 3) / 4, 256, 0, stream>>>(h_biz, rp_u, col_u, m2_user, NU);
  // 7. layer-2 GEMMs: o = relu(mean@W_l + b + h@W_r), fp32 out to d_out
  {
    float* o_user = (float*)d_out;
    float* o_biz = (float*)d_out + (size_t)NU * DOUT;
    dim3 gb((NB + 127) / 128, DOUT / 128);
    gemm2_kernel<0><<<gb, 256, 0, stream>>>(m2_biz, h_biz, w2l_ub_t, w2r_ub_t, b2_ub,
                                            o_biz, NB, DOUT, DH);
    dim3 gu((NU + 127) / 128, DOUT / 128);
    gemm2_kernel<0><<<gu, 256, 0, stream>>>(m2_user, h_user, w2l_bu_t, w2r_bu_t, b2_bu,
                                            o_user, NU, DOUT, DH);
  }
}

// Round 2
// 1246.528 us; speedup vs baseline: 1.0413x; 1.0413x over previous
//
#include <hip/hip_runtime.h>
#include <cstdint>
#include <cstddef>

typedef unsigned short u16;
typedef unsigned int u32;

typedef short bf16x8_t __attribute__((ext_vector_type(8)));
typedef float f32x4_t __attribute__((ext_vector_type(4)));

__device__ __forceinline__ u16 f2bf(float f) {
  u32 u = __float_as_uint(f);
  u += 0x7fffu + ((u >> 16) & 1u);   // round-to-nearest-even
  return (u16)(u >> 16);
}
__device__ __forceinline__ float bf_lo(u32 w) { return __uint_as_float(w << 16); }
__device__ __forceinline__ float bf_hi(u32 w) { return __uint_as_float(w & 0xffff0000u); }
__device__ __forceinline__ u32 pack2(float lo, float hi) {
  return (u32)f2bf(lo) | ((u32)f2bf(hi) << 16);
}

__device__ __forceinline__ void glds16(const u16* g, u16* l) {
  __builtin_amdgcn_global_load_lds((const __attribute__((address_space(1))) void*)g,
                                   (__attribute__((address_space(3))) void*)l, 16, 0, 0);
}

// ---------------- casts ----------------
__global__ __launch_bounds__(256) void cast_f32_to_bf16(
    const float* __restrict__ in, u16* __restrict__ out, int n4) {
  int i = blockIdx.x * 256 + threadIdx.x;
  if (i >= n4) return;
  float4 f = ((const float4*)in)[i];
  uint2 o;
  o.x = pack2(f.x, f.y);
  o.y = pack2(f.z, f.w);
  ((uint2*)out)[i] = o;
}

// Wt[n*K + k] = bf16(W[k*N + n])   (transpose + cast; small matrices)
__global__ __launch_bounds__(256) void wt_cast(
    const float* __restrict__ W, u16* __restrict__ Wt, int K, int N) {
  int id = blockIdx.x * 256 + threadIdx.x;
  if (id >= K * N) return;
  int n_ = id / K;
  int k = id - n_ * K;
  Wt[id] = f2bf(W[(size_t)k * N + n_]);
}

// ---------------- CSR build ----------------
__global__ __launch_bounds__(256) void zero_i32(int* __restrict__ p, int n) {
  int i = blockIdx.x * 256 + threadIdx.x;
  if (i < n) p[i] = 0;
}

__global__ __launch_bounds__(256) void count_kernel(
    const int* __restrict__ src, const int* __restrict__ dst,
    int* __restrict__ cb, int* __restrict__ cu, int E) {
  int e = blockIdx.x * 256 + threadIdx.x;
  if (e >= E) return;
  atomicAdd(&cb[dst[e]], 1);
  atomicAdd(&cu[src[e]], 1);
}

// one-pass scan: each thread serially owns a contiguous chunk; one block scan.
// two independent arrays handled by two concurrent blocks.
__device__ __forceinline__ void exscan_body(int* cnt, int* rp, int n) {
  __shared__ int buf[1024];
  const int tid = threadIdx.x;
  int chunk = (n + 1023) >> 10;
  int s = tid * chunk; if (s > n) s = n;
  int e = s + chunk; if (e > n) e = n;
  int sum = 0;
  for (int i = s; i < e; ++i) sum += cnt[i];
  buf[tid] = sum;
  __syncthreads();
  for (int off = 1; off < 1024; off <<= 1) {
    int t = (tid >= off) ? buf[tid - off] : 0;
    __syncthreads();
    buf[tid] += t;
    __syncthreads();
  }
  int run = (tid == 0) ? 0 : buf[tid - 1];
  for (int i = s; i < e; ++i) { int v = cnt[i]; rp[i] = run; cnt[i] = run; run += v; }
  if (tid == 0) rp[n] = buf[1023];
}

__global__ __launch_bounds__(1024) void exscan2_kernel(
    int* __restrict__ ca, int* __restrict__ rpa, int na,
    int* __restrict__ cb, int* __restrict__ rpb, int nb) {
  if (blockIdx.x == 0) exscan_body(ca, rpa, na);
  else exscan_body(cb, rpb, nb);
}

__global__ __launch_bounds__(256) void fill_kernel(
    const int* __restrict__ src, const int* __restrict__ dst,
    int* __restrict__ cb, int* __restrict__ cu,
    int* __restrict__ colb, int* __restrict__ colu, int E) {
  int e = blockIdx.x * 256 + threadIdx.x;
  if (e >= E) return;
  int s = src[e], d = dst[e];
  colb[atomicAdd(&cb[d], 1)] = s;
  colu[atomicAdd(&cu[s], 1)] = d;
}

// ---------------- segment mean, D=256 (wave per dst row) ----------------
__device__ __forceinline__ void acc4(float* a, uint2 p) {
  a[0] += bf_lo(p.x); a[1] += bf_hi(p.x);
  a[2] += bf_lo(p.y); a[3] += bf_hi(p.y);
}

__global__ __launch_bounds__(256) void agg_mean256(
    const u16* __restrict__ x, const int* __restrict__ rp,
    const int* __restrict__ col, u16* __restrict__ out, int M) {
  int wid = blockIdx.x * 4 + (threadIdx.x >> 6);
  if (wid >= M) return;
  int lane = threadIdx.x & 63;
  int s = rp[wid];
  int e = rp[wid + 1];
  float a[4] = {0.0f, 0.0f, 0.0f, 0.0f};
  const u16* xo = x + (size_t)lane * 4;
  int t = s;
  for (; t + 4 <= e; t += 4) {
    int j0 = col[t], j1 = col[t + 1], j2 = col[t + 2], j3 = col[t + 3];
    uint2 p0 = *(const uint2*)(xo + (size_t)j0 * 256);
    uint2 p1 = *(const uint2*)(xo + (size_t)j1 * 256);
    uint2 p2 = *(const uint2*)(xo + (size_t)j2 * 256);
    uint2 p3 = *(const uint2*)(xo + (size_t)j3 * 256);
    acc4(a, p0); acc4(a, p1); acc4(a, p2); acc4(a, p3);
  }
  for (; t < e; ++t) {
    uint2 p = *(const uint2*)(xo + (size_t)col[t] * 256);
    acc4(a, p);
  }
  int deg = e - s;
  float sc = 1.0f / (float)(deg > 0 ? deg : 1);
  uint2 o;
  o.x = pack2(a[0] * sc, a[1] * sc);
  o.y = pack2(a[2] * sc, a[3] * sc);
  *(uint2*)(out + (size_t)wid * 256 + (size_t)lane * 4) = o;
}

// ---------------- GEMM: C = act(sum_p A_p@B_p + [C0] + [bias]) ----------------
// A: [M][K] bf16 row-major (workspace, padded by >=128 rows). Bt: [N][K] bf16.
// 128x128 tile, 4 waves 2x2, 4x4 mfma_f32_16x16x32_bf16 per wave.
// grid.x = N/128 (fast, for A reuse in L2/L3), grid.y = M tiles.
// Staging via global_load_lds width=16, unpadded [128][32] LDS (m97 layout,
// conflict-free across quads).
template <int NA, int HAS_C0, int RELU, int OUT_BF16, int HAS_BIAS>
__global__ __launch_bounds__(256) void gemm_kernel(
    const u16* __restrict__ A1, const u16* __restrict__ A2,
    const u16* __restrict__ B1t, const u16* __restrict__ B2t,
    const u16* __restrict__ C0, const float* __restrict__ bias,
    void* __restrict__ Cout, int M, int N, int K) {
  __shared__ u16 As[128 * 32];
  __shared__ u16 Bs[128 * 32];
  const int n0 = blockIdx.x * 128;
  const int m0 = blockIdx.y * 128;
  const int tid = threadIdx.x;
  const int w = tid >> 6;
  const int lane = tid & 63;
  const int wm = (w & 1) << 6;
  const int wn = (w >> 1) << 6;
  const int quad = lane >> 4;
  const int l16 = lane & 15;
  // staging map: wave w call q covers rows w*32+q*16 + lane/4, col elems (lane%4)*8
  const int srow = (w << 5) + (lane >> 2);
  const int scol = (lane & 3) << 3;
  u16* lA = As + (w << 10);  // +512 elems for q=1
  u16* lB = Bs + (w << 10);

  f32x4_t acc[4][4];
#pragma unroll
  for (int i = 0; i < 4; ++i)
#pragma unroll
    for (int j = 0; j < 4; ++j)
#pragma unroll
      for (int r = 0; r < 4; ++r) acc[i][j][r] = 0.0f;

#pragma unroll 1
  for (int pass = 0; pass < NA; ++pass) {
    const u16* A = pass ? A2 : A1;
    const u16* Bt = pass ? B2t : B1t;
#pragma unroll 1
    for (int k0 = 0; k0 < K; k0 += 32) {
      __syncthreads();
      const u16* gA = A + (size_t)(m0 + srow) * K + k0 + scol;
      const u16* gB = Bt + (size_t)(n0 + srow) * K + k0 + scol;
      glds16(gA, lA);
      glds16(gA + (size_t)16 * K, lA + 512);
      glds16(gB, lB);
      glds16(gB + (size_t)16 * K, lB + 512);
      __syncthreads();
      bf16x8_t af[4], bfv[4];
#pragma unroll
      for (int i = 0; i < 4; ++i)
        af[i] = *(const bf16x8_t*)(As + (wm + i * 16 + l16) * 32 + (quad << 3));
#pragma unroll
      for (int j = 0; j < 4; ++j)
        bfv[j] = *(const bf16x8_t*)(Bs + (wn + j * 16 + l16) * 32 + (quad << 3));
#pragma unroll
      for (int i = 0; i < 4; ++i)
#pragma unroll
        for (int j = 0; j < 4; ++j)
          acc[i][j] = __builtin_amdgcn_mfma_f32_16x16x32_bf16(af[i], bfv[j], acc[i][j], 0, 0, 0);
    }
  }

  // epilogue: C/D layout col=lane&15, row=(lane>>4)*4+r
#pragma unroll
  for (int i = 0; i < 4; ++i) {
    int row = m0 + wm + i * 16 + (quad << 2);
#pragma unroll
    for (int j = 0; j < 4; ++j) {
      int colg = n0 + wn + j * 16 + l16;
      float b = HAS_BIAS ? bias[colg] : 0.0f;
#pragma unroll
      for (int r = 0; r < 4; ++r) {
        if (row + r < M) {
          float v = acc[i][j][r] + b;
          if (HAS_C0) v += bf_lo((u32)C0[(size_t)(row + r) * N + colg]);
          if (RELU) v = fmaxf(v, 0.0f);
          if (OUT_BF16)
            ((u16*)Cout)[(size_t)(row + r) * N + colg] = f2bf(v);
          else
            ((float*)Cout)[(size_t)(row + r) * N + colg] = v;
        }
      }
    }
  }
}

// ---------------- launch ----------------
extern "C" void kernel_launch(void* const* d_in, const int* in_sizes, int n_in,
                              void* d_out, int out_size, void* d_ws, size_t ws_size,
                              hipStream_t stream) {
  const int DIN = 256, DH = 512, DOUT = 256;
  const int NU = in_sizes[0] / DIN;
  const int NB = in_sizes[1] / DIN;
  const int E = in_sizes[2];

  const float* x_user = (const float*)d_in[0];
  const float* x_biz = (const float*)d_in[1];
  const int* e_src = (const int*)d_in[2];
  const int* e_dst = (const int*)d_in[3];
  const float* W1l_ub = (const float*)d_in[4];
  const float* W1r_ub = (const float*)d_in[5];
  const float* b1_ub = (const float*)d_in[6];
  const float* W1l_bu = (const float*)d_in[7];
  const float* W1r_bu = (const float*)d_in[8];
  const float* b1_bu = (const float*)d_in[9];
  const float* W2l_ub = (const float*)d_in[10];
  const float* W2r_ub = (const float*)d_in[11];
  const float* b2_ub = (const float*)d_in[12];
  const float* W2l_bu = (const float*)d_in[13];
  const float* W2r_bu = (const float*)d_in[14];
  const float* b2_bu = (const float*)d_in[15];

  char* base = (char*)d_ws;
  size_t off = 0;
  auto alloc = [&](size_t bytes) -> char* {
    char* r = base + off;
    off += (bytes + 255) & ~(size_t)255;
    return r;
  };
  const size_t MARGIN = (size_t)128 * 512 * 2;  // 128 rows of widest matrix

  int* rp_b = (int*)alloc((size_t)(NB + 1) * 4);
  int* rp_u = (int*)alloc((size_t)(NU + 1) * 4);
  int* cur_b = (int*)alloc((size_t)NB * 4);
  int* cur_u = (int*)alloc((size_t)NU * 4);
  int* col_b = (int*)alloc((size_t)E * 4);
  int* col_u = (int*)alloc((size_t)E * 4);
  u16* w1l_ub_t = (u16*)alloc((size_t)DIN * DH * 2);
  u16* w1r_ub_t = (u16*)alloc((size_t)DIN * DH * 2);
  u16* w1l_bu_t = (u16*)alloc((size_t)DIN * DH * 2);
  u16* w1r_bu_t = (u16*)alloc((size_t)DIN * DH * 2);
  u16* w2l_ub_t = (u16*)alloc((size_t)DH * DOUT * 2);
  u16* w2r_ub_t = (u16*)alloc((size_t)DH * DOUT * 2);
  u16* w2l_bu_t = (u16*)alloc((size_t)DH * DOUT * 2);
  u16* w2r_bu_t = (u16*)alloc((size_t)DH * DOUT * 2);
  u16* x_user_bf = (u16*)alloc((size_t)NU * DIN * 2 + MARGIN);
  u16* x_biz_bf = (u16*)alloc((size_t)NB * DIN * 2 + MARGIN);
  u16* m1_biz = (u16*)alloc((size_t)NB * DIN * 2 + MARGIN);
  u16* m1_user = (u16*)alloc((size_t)NU * DIN * 2 + MARGIN);
  u16* h_biz = (u16*)alloc((size_t)NB * DH * 2 + MARGIN);
  u16* h_user = (u16*)alloc((size_t)NU * DH * 2 + MARGIN);
  // layer-2 aliases onto dead layer-1 buffers (sizes match exactly):
  u16* t_user = x_user_bf;   // NU x DOUT bf16, h_user @ W2l_ub
  u16* t_biz = x_biz_bf;     // NB x DOUT bf16, h_biz @ W2l_bu
  u16* m2t_biz = m1_biz;     // NB x DOUT
  u16* m2t_user = m1_user;   // NU x DOUT
  if (off > ws_size) return;

  // 1. cast node features to bf16
  {
    int n4u = NU * DIN / 4, n4b = NB * DIN / 4;
    cast_f32_to_bf16<<<(n4u + 255) / 256, 256, 0, stream>>>(x_user, x_user_bf, n4u);
    cast_f32_to_bf16<<<(n4b + 255) / 256, 256, 0, stream>>>(x_biz, x_biz_bf, n4b);
  }
  // 2. transpose+cast weights
  {
    int kn1 = DIN * DH, kn2 = DH * DOUT;
    wt_cast<<<(kn1 + 255) / 256, 256, 0, stream>>>(W1l_ub, w1l_ub_t, DIN, DH);
    wt_cast<<<(kn1 + 255) / 256, 256, 0, stream>>>(W1r_ub, w1r_ub_t, DIN, DH);
    wt_cast<<<(kn1 + 255) / 256, 256, 0, stream>>>(W1l_bu, w1l_bu_t, DIN, DH);
    wt_cast<<<(kn1 + 255) / 256, 256, 0, stream>>>(W1r_bu, w1r_bu_t, DIN, DH);
    wt_cast<<<(kn2 + 255) / 256, 256, 0, stream>>>(W2l_ub, w2l_ub_t, DH, DOUT);
    wt_cast<<<(kn2 + 255) / 256, 256, 0, stream>>>(W2r_ub, w2r_ub_t, DH, DOUT);
    wt_cast<<<(kn2 + 255) / 256, 256, 0, stream>>>(W2l_bu, w2l_bu_t, DH, DOUT);
    wt_cast<<<(kn2 + 255) / 256, 256, 0, stream>>>(W2r_bu, w2r_bu_t, DH, DOUT);
  }
  // 3. CSR build
  zero_i32<<<(NB + 255) / 256, 256, 0, stream>>>(cur_b, NB);
  zero_i32<<<(NU + 255) / 256, 256, 0, stream>>>(cur_u, NU);
  count_kernel<<<(E + 255) / 256, 256, 0, stream>>>(e_src, e_dst, cur_b, cur_u, E);
  exscan2_kernel<<<2, 1024, 0, stream>>>(cur_b, rp_b, NB, cur_u, rp_u, NU);
  fill_kernel<<<(E + 255) / 256, 256, 0, stream>>>(e_src, e_dst, cur_b, cur_u, col_b, col_u, E);
  // 4. layer-1 aggregation (mean over D=256 features)
  agg_mean256<<<(NB + 3) / 4, 256, 0, stream>>>(x_user_bf, rp_b, col_b, m1_biz, NB);
  agg_mean256<<<(NU + 3) / 4, 256, 0, stream>>>(x_biz_bf, rp_u, col_u, m1_user, NU);
  // 5. layer-1 GEMMs: h = relu(mean@W1l + x@W1r + b), bf16 out
  {
    dim3 gb(DH / 128, (NB + 127) / 128);
    gemm_kernel<2, 0, 1, 1, 1><<<gb, 256, 0, stream>>>(
        m1_biz, x_biz_bf, w1l_ub_t, w1r_ub_t, nullptr, b1_ub, h_biz, NB, DH, DIN);
    dim3 gu(DH / 128, (NU + 127) / 128);
    gemm_kernel<2, 0, 1, 1, 1><<<gu, 256, 0, stream>>>(
        m1_user, x_user_bf, w1l_bu_t, w1r_bu_t, nullptr, b1_bu, h_user, NU, DH, DIN);
  }
  // 6. layer-2 transform-first: t = h @ W2l (mean is linear -> aggregate t at D=256)
  {
    dim3 gu(DOUT / 128, (NU + 127) / 128);
    gemm_kernel<1, 0, 0, 1, 0><<<gu, 256, 0, stream>>>(
        h_user, nullptr, w2l_ub_t, nullptr, nullptr, nullptr, t_user, NU, DOUT, DH);
    dim3 gb(DOUT / 128, (NB + 127) / 128);
    gemm_kernel<1, 0, 0, 1, 0><<<gb, 256, 0, stream>>>(
        h_biz, nullptr, w2l_bu_t, nullptr, nullptr, nullptr, t_biz, NB, DOUT, DH);
  }
  // 7. layer-2 aggregation (mean over D=256 transformed features)
  agg_mean256<<<(NB + 3) / 4, 256, 0, stream>>>(t_user, rp_b, col_b, m2t_biz, NB);
  agg_mean256<<<(NU + 3) / 4, 256, 0, stream>>>(t_biz, rp_u, col_u, m2t_user, NU);
  // 8. layer-2 output GEMMs: o = relu(h@W2r + m2t + b), fp32 out to d_out
  {
    float* o_user = (float*)d_out;
    float* o_biz = (float*)d_out + (size_t)NU * DOUT;
    dim3 gb(DOUT / 128, (NB + 127) / 128);
    gemm_kernel<1, 1, 1, 0, 1><<<gb, 256, 0, stream>>>(
        h_biz, nullptr, w2r_ub_t, nullptr, m2t_biz, b2_ub, o_biz, NB, DOUT, DH);
    dim3 gu(DOUT / 128, (NU + 127) / 128);
    gemm_kernel<1, 1, 1, 0, 1><<<gu, 256, 0, stream>>>(
        h_user, nullptr, w2r_bu_t, nullptr, m2t_user, b2_bu, o_user, NU, DOUT, DH);
  }
}

// Round 3
// 1023.776 us; speedup vs baseline: 1.2678x; 1.2176x over previous
//
#include <hip/hip_runtime.h>
#include <cstdint>
#include <cstddef>

typedef unsigned short u16;
typedef unsigned int u32;

typedef short bf16x8_t __attribute__((ext_vector_type(8)));
typedef float f32x4_t __attribute__((ext_vector_type(4)));

__device__ __forceinline__ u16 f2bf(float f) {
  u32 u = __float_as_uint(f);
  u += 0x7fffu + ((u >> 16) & 1u);   // round-to-nearest-even
  return (u16)(u >> 16);
}
__device__ __forceinline__ float bf_lo(u32 w) { return __uint_as_float(w << 16); }
__device__ __forceinline__ float bf_hi(u32 w) { return __uint_as_float(w & 0xffff0000u); }
__device__ __forceinline__ u32 pack2(float lo, float hi) {
  return (u32)f2bf(lo) | ((u32)f2bf(hi) << 16);
}

__device__ __forceinline__ void glds16(const u16* g, u16* l) {
  __builtin_amdgcn_global_load_lds((const __attribute__((address_space(1))) void*)g,
                                   (__attribute__((address_space(3))) void*)l, 16, 0, 0);
}

// ---------------- casts ----------------
__global__ __launch_bounds__(256) void cast_f32_to_bf16(
    const float* __restrict__ in, u16* __restrict__ out, int n4) {
  int i = blockIdx.x * 256 + threadIdx.x;
  if (i >= n4) return;
  float4 f = ((const float4*)in)[i];
  uint2 o;
  o.x = pack2(f.x, f.y);
  o.y = pack2(f.z, f.w);
  ((uint2*)out)[i] = o;
}

// Wt[n*K + k] = bf16(W[k*N + n])   (transpose + cast; small matrices)
__global__ __launch_bounds__(256) void wt_cast(
    const float* __restrict__ W, u16* __restrict__ Wt, int K, int N) {
  int id = blockIdx.x * 256 + threadIdx.x;
  if (id >= K * N) return;
  int n_ = id / K;
  int k = id - n_ * K;
  Wt[id] = f2bf(W[(size_t)k * N + n_]);
}

// ---------------- CSR build ----------------
__global__ __launch_bounds__(256) void zero_i32(int* __restrict__ p, int n) {
  int i = blockIdx.x * 256 + threadIdx.x;
  if (i < n) p[i] = 0;
}

__global__ __launch_bounds__(256) void count_kernel(
    const int* __restrict__ src, const int* __restrict__ dst,
    int* __restrict__ cb, int* __restrict__ cu, int E) {
  int e = blockIdx.x * 256 + threadIdx.x;
  if (e >= E) return;
  atomicAdd(&cb[dst[e]], 1);
  atomicAdd(&cu[src[e]], 1);
}

// hierarchical scan, stage 1: per-1024-tile sums (coalesced int4 reads).
// grid (maxTiles, 2): y selects which array. n must be a multiple of 4.
__global__ __launch_bounds__(256) void tile_sums(
    const int* __restrict__ c0, int* __restrict__ p0, int nt0, int n0,
    const int* __restrict__ c1, int* __restrict__ p1, int nt1, int n1) {
  const int* c = blockIdx.y ? c1 : c0;
  int* p = blockIdx.y ? p1 : p0;
  const int nt = blockIdx.y ? nt1 : nt0;
  const int n = blockIdx.y ? n1 : n0;
  if ((int)blockIdx.x >= nt) return;
  int base = blockIdx.x * 1024 + threadIdx.x * 4;
  int4 v = {0, 0, 0, 0};
  if (base < n) v = *(const int4*)(c + base);
  int s = v.x + v.y + v.z + v.w;
  for (int off = 32; off; off >>= 1) s += __shfl_down(s, off, 64);
  __shared__ int ws[4];
  int lane = threadIdx.x & 63, w = threadIdx.x >> 6;
  if (lane == 0) ws[w] = s;
  __syncthreads();
  if (threadIdx.x == 0) p[blockIdx.x] = ws[0] + ws[1] + ws[2] + ws[3];
}

// stage 2: exclusive-scan the partials (<=128 per array); writes rp[n]=total.
__global__ __launch_bounds__(128) void scan_partials(
    int* __restrict__ p0, int np0, int* __restrict__ rp0, int n0,
    int* __restrict__ p1, int np1, int* __restrict__ rp1, int n1) {
  int* p = blockIdx.x ? p1 : p0;
  const int np = blockIdx.x ? np1 : np0;
  int* rp = blockIdx.x ? rp1 : rp0;
  const int n = blockIdx.x ? n1 : n0;
  __shared__ int buf[128];
  int tid = threadIdx.x;
  int v = (tid < np) ? p[tid] : 0;
  buf[tid] = v;
  __syncthreads();
  for (int off = 1; off < 128; off <<= 1) {
    int t = (tid >= off) ? buf[tid - off] : 0;
    __syncthreads();
    buf[tid] += t;
    __syncthreads();
  }
  if (tid < np) p[tid] = buf[tid] - v;  // exclusive tile base
  if (tid == 0) rp[n] = buf[127];
}

// stage 3: block-local exclusive scan + tile base -> rp and cur.
__global__ __launch_bounds__(256) void scan_apply(
    const int* __restrict__ c0, const int* __restrict__ p0,
    int* __restrict__ rp0, int* __restrict__ cur0, int nt0, int n0,
    const int* __restrict__ c1, const int* __restrict__ p1,
    int* __restrict__ rp1, int* __restrict__ cur1, int nt1, int n1) {
  const int* c = blockIdx.y ? c1 : c0;
  const int* p = blockIdx.y ? p1 : p0;
  int* rp = blockIdx.y ? rp1 : rp0;
  int* cur = blockIdx.y ? cur1 : cur0;
  const int nt = blockIdx.y ? nt1 : nt0;
  const int n = blockIdx.y ? n1 : n0;
  if ((int)blockIdx.x >= nt) return;
  int base = blockIdx.x * 1024 + threadIdx.x * 4;
  int4 v = {0, 0, 0, 0};
  if (base < n) v = *(const int4*)(c + base);
  int s = v.x + v.y + v.z + v.w;
  int lane = threadIdx.x & 63, w = threadIdx.x >> 6;
  int incl = s;
  for (int off = 1; off < 64; off <<= 1) {
    int t = __shfl_up(incl, off, 64);
    if (lane >= off) incl += t;
  }
  __shared__ int ws[4];
  if (lane == 63) ws[w] = incl;
  __syncthreads();
  int woff = 0;
#pragma unroll
  for (int q = 0; q < 4; ++q)
    if (q < w) woff += ws[q];
  int excl = incl - s + woff + p[blockIdx.x];
  if (base < n) {
    int4 r;
    r.x = excl;
    r.y = excl + v.x;
    r.z = r.y + v.y;
    r.w = r.z + v.z;
    *(int4*)(rp + base) = r;
    *(int4*)(cur + base) = r;
  }
}

__global__ __launch_bounds__(256) void fill_kernel(
    const int* __restrict__ src, const int* __restrict__ dst,
    int* __restrict__ cb, int* __restrict__ cu,
    int* __restrict__ colb, int* __restrict__ colu, int E) {
  int e = blockIdx.x * 256 + threadIdx.x;
  if (e >= E) return;
  int s = src[e], d = dst[e];
  colb[atomicAdd(&cb[d], 1)] = s;
  colu[atomicAdd(&cu[s], 1)] = d;
}

// ---------------- segment mean, D=256 (wave per dst row), dual-graph fused ----------------
__device__ __forceinline__ void acc4(float* a, uint2 p) {
  a[0] += bf_lo(p.x); a[1] += bf_hi(p.x);
  a[2] += bf_lo(p.y); a[3] += bf_hi(p.y);
}

__global__ __launch_bounds__(256) void agg_mean256_dual(
    const u16* __restrict__ xa, const int* __restrict__ rpa,
    const int* __restrict__ cola, u16* __restrict__ outa, int Ma,
    const u16* __restrict__ xb, const int* __restrict__ rpb,
    const int* __restrict__ colb, u16* __restrict__ outb, int Mb) {
  const int nblk_a = (Ma + 3) >> 2;
  const u16* x;
  const int *rp, *col;
  u16* out;
  int M, wid0;
  if ((int)blockIdx.x < nblk_a) {
    x = xa; rp = rpa; col = cola; out = outa; M = Ma; wid0 = blockIdx.x * 4;
  } else {
    x = xb; rp = rpb; col = colb; out = outb; M = Mb; wid0 = (blockIdx.x - nblk_a) * 4;
  }
  int wid = wid0 + (threadIdx.x >> 6);
  if (wid >= M) return;
  int lane = threadIdx.x & 63;
  int s = rp[wid];
  int e = rp[wid + 1];
  float a[4] = {0.0f, 0.0f, 0.0f, 0.0f};
  const u16* xo = x + (size_t)lane * 4;
  int t = s;
  for (; t + 4 <= e; t += 4) {
    int j0 = col[t], j1 = col[t + 1], j2 = col[t + 2], j3 = col[t + 3];
    uint2 p0 = *(const uint2*)(xo + (size_t)j0 * 256);
    uint2 p1 = *(const uint2*)(xo + (size_t)j1 * 256);
    uint2 p2 = *(const uint2*)(xo + (size_t)j2 * 256);
    uint2 p3 = *(const uint2*)(xo + (size_t)j3 * 256);
    acc4(a, p0); acc4(a, p1); acc4(a, p2); acc4(a, p3);
  }
  for (; t < e; ++t) {
    uint2 p = *(const uint2*)(xo + (size_t)col[t] * 256);
    acc4(a, p);
  }
  int deg = e - s;
  float sc = 1.0f / (float)(deg > 0 ? deg : 1);
  uint2 o;
  o.x = pack2(a[0] * sc, a[1] * sc);
  o.y = pack2(a[2] * sc, a[3] * sc);
  *(uint2*)(out + (size_t)wid * 256 + (size_t)lane * 4) = o;
}

// ---------------- GEMM: C = act(sum_p A_p@B_p + [C0] + [bias]) ----------------
// A: [M][K] bf16 row-major (workspace, padded by >=128 rows). Bt: [N][K] bf16.
// 128x128 tile, 4 waves 2x2, 4x4 mfma_f32_16x16x32_bf16 per wave.
// grid.x = N/128 (fast, for A reuse in L2/L3), grid.y = M tiles.
// Staging via global_load_lds width=16, unpadded [128][32] LDS.
template <int NA, int HAS_C0, int RELU, int OUT_BF16, int HAS_BIAS>
__global__ __launch_bounds__(256) void gemm_kernel(
    const u16* __restrict__ A1, const u16* __restrict__ A2,
    const u16* __restrict__ B1t, const u16* __restrict__ B2t,
    const u16* __restrict__ C0, const float* __restrict__ bias,
    void* __restrict__ Cout, int M, int N, int K) {
  __shared__ u16 As[128 * 32];
  __shared__ u16 Bs[128 * 32];
  const int n0 = blockIdx.x * 128;
  const int m0 = blockIdx.y * 128;
  const int tid = threadIdx.x;
  const int w = tid >> 6;
  const int lane = tid & 63;
  const int wm = (w & 1) << 6;
  const int wn = (w >> 1) << 6;
  const int quad = lane >> 4;
  const int l16 = lane & 15;
  const int srow = (w << 5) + (lane >> 2);
  const int scol = (lane & 3) << 3;
  u16* lA = As + (w << 10);
  u16* lB = Bs + (w << 10);

  f32x4_t acc[4][4];
#pragma unroll
  for (int i = 0; i < 4; ++i)
#pragma unroll
    for (int j = 0; j < 4; ++j)
#pragma unroll
      for (int r = 0; r < 4; ++r) acc[i][j][r] = 0.0f;

#pragma unroll 1
  for (int pass = 0; pass < NA; ++pass) {
    const u16* A = pass ? A2 : A1;
    const u16* Bt = pass ? B2t : B1t;
#pragma unroll 1
    for (int k0 = 0; k0 < K; k0 += 32) {
      __syncthreads();
      const u16* gA = A + (size_t)(m0 + srow) * K + k0 + scol;
      const u16* gB = Bt + (size_t)(n0 + srow) * K + k0 + scol;
      glds16(gA, lA);
      glds16(gA + (size_t)16 * K, lA + 512);
      glds16(gB, lB);
      glds16(gB + (size_t)16 * K, lB + 512);
      __syncthreads();
      bf16x8_t af[4], bfv[4];
#pragma unroll
      for (int i = 0; i < 4; ++i)
        af[i] = *(const bf16x8_t*)(As + (wm + i * 16 + l16) * 32 + (quad << 3));
#pragma unroll
      for (int j = 0; j < 4; ++j)
        bfv[j] = *(const bf16x8_t*)(Bs + (wn + j * 16 + l16) * 32 + (quad << 3));
#pragma unroll
      for (int i = 0; i < 4; ++i)
#pragma unroll
        for (int j = 0; j < 4; ++j)
          acc[i][j] = __builtin_amdgcn_mfma_f32_16x16x32_bf16(af[i], bfv[j], acc[i][j], 0, 0, 0);
    }
  }

  // epilogue: C/D layout col=lane&15, row=(lane>>4)*4+r
#pragma unroll
  for (int i = 0; i < 4; ++i) {
    int row = m0 + wm + i * 16 + (quad << 2);
#pragma unroll
    for (int j = 0; j < 4; ++j) {
      int colg = n0 + wn + j * 16 + l16;
      float b = HAS_BIAS ? bias[colg] : 0.0f;
#pragma unroll
      for (int r = 0; r < 4; ++r) {
        if (row + r < M) {
          float v = acc[i][j][r] + b;
          if (HAS_C0) v += bf_lo((u32)C0[(size_t)(row + r) * N + colg]);
          if (RELU) v = fmaxf(v, 0.0f);
          if (OUT_BF16)
            ((u16*)Cout)[(size_t)(row + r) * N + colg] = f2bf(v);
          else
            ((float*)Cout)[(size_t)(row + r) * N + colg] = v;
        }
      }
    }
  }
}

// ---------------- launch ----------------
extern "C" void kernel_launch(void* const* d_in, const int* in_sizes, int n_in,
                              void* d_out, int out_size, void* d_ws, size_t ws_size,
                              hipStream_t stream) {
  const int DIN = 256, DH = 512, DOUT = 256;
  const int NU = in_sizes[0] / DIN;
  const int NB = in_sizes[1] / DIN;
  const int E = in_sizes[2];

  const float* x_user = (const float*)d_in[0];
  const float* x_biz = (const float*)d_in[1];
  const int* e_src = (const int*)d_in[2];
  const int* e_dst = (const int*)d_in[3];
  const float* W1l_ub = (const float*)d_in[4];
  const float* W1r_ub = (const float*)d_in[5];
  const float* b1_ub = (const float*)d_in[6];
  const float* W1l_bu = (const float*)d_in[7];
  const float* W1r_bu = (const float*)d_in[8];
  const float* b1_bu = (const float*)d_in[9];
  const float* W2l_ub = (const float*)d_in[10];
  const float* W2r_ub = (const float*)d_in[11];
  const float* b2_ub = (const float*)d_in[12];
  const float* W2l_bu = (const float*)d_in[13];
  const float* W2r_bu = (const float*)d_in[14];
  const float* b2_bu = (const float*)d_in[15];

  char* base = (char*)d_ws;
  size_t off = 0;
  auto alloc = [&](size_t bytes) -> char* {
    char* r = base + off;
    off += (bytes + 255) & ~(size_t)255;
    return r;
  };
  const size_t MARGIN = (size_t)128 * 512 * 2;  // 128 rows of widest matrix

  int* rp_b = (int*)alloc((size_t)(NB + 1) * 4);
  int* rp_u = (int*)alloc((size_t)(NU + 1) * 4);
  int* cur_b = (int*)alloc((size_t)NB * 4);
  int* cur_u = (int*)alloc((size_t)NU * 4);
  int* part_b = (int*)alloc(128 * 4);
  int* part_u = (int*)alloc(128 * 4);
  int* col_b = (int*)alloc((size_t)E * 4);
  int* col_u = (int*)alloc((size_t)E * 4);
  u16* w1l_ub_t = (u16*)alloc((size_t)DIN * DH * 2);
  u16* w1r_ub_t = (u16*)alloc((size_t)DIN * DH * 2);
  u16* w1l_bu_t = (u16*)alloc((size_t)DIN * DH * 2);
  u16* w1r_bu_t = (u16*)alloc((size_t)DIN * DH * 2);
  u16* w2l_ub_t = (u16*)alloc((size_t)DH * DOUT * 2);
  u16* w2r_ub_t = (u16*)alloc((size_t)DH * DOUT * 2);
  u16* w2l_bu_t = (u16*)alloc((size_t)DH * DOUT * 2);
  u16* w2r_bu_t = (u16*)alloc((size_t)DH * DOUT * 2);
  u16* x_user_bf = (u16*)alloc((size_t)NU * DIN * 2 + MARGIN);
  u16* x_biz_bf = (u16*)alloc((size_t)NB * DIN * 2 + MARGIN);
  u16* m1_biz = (u16*)alloc((size_t)NB * DIN * 2 + MARGIN);
  u16* m1_user = (u16*)alloc((size_t)NU * DIN * 2 + MARGIN);
  u16* h_biz = (u16*)alloc((size_t)NB * DH * 2 + MARGIN);
  u16* h_user = (u16*)alloc((size_t)NU * DH * 2 + MARGIN);
  // layer-2 aliases onto dead layer-1 buffers (sizes match exactly):
  u16* t_user = x_user_bf;   // NU x DOUT bf16, h_user @ W2l_ub
  u16* t_biz = x_biz_bf;     // NB x DOUT bf16, h_biz @ W2l_bu
  u16* m2t_biz = m1_biz;     // NB x DOUT
  u16* m2t_user = m1_user;   // NU x DOUT
  if (off > ws_size) return;

  const int nt_b = (NB + 1023) / 1024;  // 49
  const int nt_u = (NU + 1023) / 1024;  // 98

  // 1. cast node features to bf16
  {
    int n4u = NU * DIN / 4, n4b = NB * DIN / 4;
    cast_f32_to_bf16<<<(n4u + 255) / 256, 256, 0, stream>>>(x_user, x_user_bf, n4u);
    cast_f32_to_bf16<<<(n4b + 255) / 256, 256, 0, stream>>>(x_biz, x_biz_bf, n4b);
  }
  // 2. transpose+cast weights
  {
    int kn1 = DIN * DH, kn2 = DH * DOUT;
    wt_cast<<<(kn1 + 255) / 256, 256, 0, stream>>>(W1l_ub, w1l_ub_t, DIN, DH);
    wt_cast<<<(kn1 + 255) / 256, 256, 0, stream>>>(W1r_ub, w1r_ub_t, DIN, DH);
    wt_cast<<<(kn1 + 255) / 256, 256, 0, stream>>>(W1l_bu, w1l_bu_t, DIN, DH);
    wt_cast<<<(kn1 + 255) / 256, 256, 0, stream>>>(W1r_bu, w1r_bu_t, DIN, DH);
    wt_cast<<<(kn2 + 255) / 256, 256, 0, stream>>>(W2l_ub, w2l_ub_t, DH, DOUT);
    wt_cast<<<(kn2 + 255) / 256, 256, 0, stream>>>(W2r_ub, w2r_ub_t, DH, DOUT);
    wt_cast<<<(kn2 + 255) / 256, 256, 0, stream>>>(W2l_bu, w2l_bu_t, DH, DOUT);
    wt_cast<<<(kn2 + 255) / 256, 256, 0, stream>>>(W2r_bu, w2r_bu_t, DH, DOUT);
  }
  // 3. CSR build (hierarchical parallel scan)
  zero_i32<<<(NB + 255) / 256, 256, 0, stream>>>(cur_b, NB);
  zero_i32<<<(NU + 255) / 256, 256, 0, stream>>>(cur_u, NU);
  count_kernel<<<(E + 255) / 256, 256, 0, stream>>>(e_src, e_dst, cur_b, cur_u, E);
  tile_sums<<<dim3(nt_u, 2), 256, 0, stream>>>(cur_b, part_b, nt_b, NB,
                                               cur_u, part_u, nt_u, NU);
  scan_partials<<<2, 128, 0, stream>>>(part_b, nt_b, rp_b, NB,
                                       part_u, nt_u, rp_u, NU);
  scan_apply<<<dim3(nt_u, 2), 256, 0, stream>>>(cur_b, part_b, rp_b, cur_b, nt_b, NB,
                                                cur_u, part_u, rp_u, cur_u, nt_u, NU);
  fill_kernel<<<(E + 255) / 256, 256, 0, stream>>>(e_src, e_dst, cur_b, cur_u, col_b, col_u, E);
  // 4. layer-1 aggregation (mean over D=256 features), both directions fused
  {
    int nblk = (NB + 3) / 4 + (NU + 3) / 4;
    agg_mean256_dual<<<nblk, 256, 0, stream>>>(x_user_bf, rp_b, col_b, m1_biz, NB,
                                               x_biz_bf, rp_u, col_u, m1_user, NU);
  }
  // 5. layer-1 GEMMs: h = relu(mean@W1l + x@W1r + b), bf16 out
  {
    dim3 gb(DH / 128, (NB + 127) / 128);
    gemm_kernel<2, 0, 1, 1, 1><<<gb, 256, 0, stream>>>(
        m1_biz, x_biz_bf, w1l_ub_t, w1r_ub_t, nullptr, b1_ub, h_biz, NB, DH, DIN);
    dim3 gu(DH / 128, (NU + 127) / 128);
    gemm_kernel<2, 0, 1, 1, 1><<<gu, 256, 0, stream>>>(
        m1_user, x_user_bf, w1l_bu_t, w1r_bu_t, nullptr, b1_bu, h_user, NU, DH, DIN);
  }
  // 6. layer-2 transform-first: t = h @ W2l (mean is linear -> aggregate t at D=256)
  {
    dim3 gu(DOUT / 128, (NU + 127) / 128);
    gemm_kernel<1, 0, 0, 1, 0><<<gu, 256, 0, stream>>>(
        h_user, nullptr, w2l_ub_t, nullptr, nullptr, nullptr, t_user, NU, DOUT, DH);
    dim3 gb(DOUT / 128, (NB + 127) / 128);
    gemm_kernel<1, 0, 0, 1, 0><<<gb, 256, 0, stream>>>(
        h_biz, nullptr, w2l_bu_t, nullptr, nullptr, nullptr, t_biz, NB, DOUT, DH);
  }
  // 7. layer-2 aggregation (mean over D=256 transformed features), fused
  {
    int nblk = (NB + 3) / 4 + (NU + 3) / 4;
    agg_mean256_dual<<<nblk, 256, 0, stream>>>(t_user, rp_b, col_b, m2t_biz, NB,
                                               t_biz, rp_u, col_u, m2t_user, NU);
  }
  // 8. layer-2 output GEMMs: o = relu(h@W2r + m2t + b), fp32 out to d_out
  {
    float* o_user = (float*)d_out;
    float* o_biz = (float*)d_out + (size_t)NU * DOUT;
    dim3 gb(DOUT / 128, (NB + 127) / 128);
    gemm_kernel<1, 1, 1, 0, 1><<<gb, 256, 0, stream>>>(
        h_biz, nullptr, w2r_ub_t, nullptr, m2t_biz, b2_ub, o_biz, NB, DOUT, DH);
    dim3 gu(DOUT / 128, (NU + 127) / 128);
    gemm_kernel<1, 1, 1, 0, 1><<<gu, 256, 0, stream>>>(
        h_user, nullptr, w2r_bu_t, nullptr, m2t_user, b2_bu, o_user, NU, DOUT, DH);
  }
}